// Round 14
// baseline (281.235 us; speedup 1.0000x reference)
//
#include <hip/hip_runtime.h>
#include <cstdint>
#include <math.h>

#define NQ 900
#define NT 128
#define NC 91
#define KROWS 15   // ceil(900/64)
#define NCH 10     // row chunks (900/10 = 90 rows each)
#define RPC 90     // rows per chunk

typedef unsigned long long u64;
typedef unsigned int u32;

// monotone (total-order-preserving) mapping f32 -> u32
__device__ __forceinline__ u32 fmono(float f){
  u32 u = __float_as_uint(f);
  return (u & 0x80000000u) ? ~u : (u | 0x80000000u);
}
__device__ __forceinline__ float fmono_inv(u32 m){
  u32 u = (m & 0x80000000u) ? (m & 0x7FFFFFFFu) : ~m;
  return __uint_as_float(u);
}

// ---- wave64 argmin via DPP f32 min + ballot tie-resolve (proven R10, absmax 0.0) ----
// Tie rule: among lanes with lv==gv, smallest meta wins == (val,row,col)
// flat-argmin order; stale bit 24 makes bounds lose ties to fresh keys.
__device__ __forceinline__ u32 wave_argmin(float lv, u32 lm, float* gout){
  float x = lv;
  #define FSTG(C,RM) { int t_ = __builtin_amdgcn_update_dpp(__float_as_int(x), __float_as_int(x), C, RM, 0xf, false); x = fminf(x, __int_as_float(t_)); }
  FSTG(0x111,0xf) FSTG(0x112,0xf) FSTG(0x114,0xf) FSTG(0x118,0xf)
  FSTG(0x142,0xa) FSTG(0x143,0xc)
  #undef FSTG
  float gv = __int_as_float(__builtin_amdgcn_readlane(__float_as_int(x), 63));
  *gout = gv;
  u64 tie = __ballot(lv == gv);
  if (__popcll(tie) == 1){
    int w = (int)__ffsll((long long)tie) - 1;
    return (u32)__builtin_amdgcn_readlane((int)lm, w);
  }
  u32 m = (lv == gv) ? lm : 0xFFFFFFFFu;
  #define USTG(C,RM) { u32 t_ = (u32)__builtin_amdgcn_update_dpp((int)m, (int)m, C, RM, 0xf, false); m = t_ < m ? t_ : m; }
  USTG(0x111,0xf) USTG(0x112,0xf) USTG(0x114,0xf) USTG(0x118,0xf)
  USTG(0x142,0xa) USTG(0x143,0xc)
  #undef USTG
  return (u32)__builtin_amdgcn_readlane((int)m, 63);
}

// ---------------- kernel 0: per-(b,q) softmax max & denom (UNCHANGED — bit-exact) ----------------
__global__ void softmax_stats_kernel(const float* __restrict__ logits,
                                     float* __restrict__ stats, int nrows){
  int gw   = (int)((blockIdx.x * blockDim.x + threadIdx.x) >> 6);
  int lane = threadIdx.x & 63;
  if (gw >= nrows) return;
  const float* row = logits + (size_t)gw * NC;
  float v0 = (lane      < NC) ? row[lane]      : -INFINITY;
  float v1 = (lane + 64 < NC) ? row[lane + 64] : -INFINITY;
  float m = fmaxf(v0, v1);
  #pragma unroll
  for (int off = 32; off; off >>= 1) m = fmaxf(m, __shfl_xor(m, off));
  float s = ((lane < NC) ? expf(v0 - m) : 0.0f)
          + ((lane + 64 < NC) ? expf(v1 - m) : 0.0f);
  #pragma unroll
  for (int off = 32; off; off >>= 1) s += __shfl_xor(s, off);
  if (lane == 0){ stats[2*gw] = m; stats[2*gw+1] = s; }
}

// ---------------- kernel 1: fused cost matrix + per-column chunk argmin ----------------
// Block (b,ch) = 128 threads (thread = column t), rows ch*90..ch*90+89 serial.
// Cost op order byte-identical to the validated kernel; loop-invariant target
// terms hoisted (identical values/ops). Writes Cmat coalesced + one u64 partial.
__global__ __launch_bounds__(128) void cost_colmin_kernel(
    const float* __restrict__ logits, const float* __restrict__ pboxes,
    const int*   __restrict__ labels, const float* __restrict__ tboxes,
    const float* __restrict__ stats,  float* __restrict__ Cout,
    u64* __restrict__ part){
#pragma clang fp contract(off)
  int blk = blockIdx.x;
  int b = blk / NCH, ch = blk - b * NCH;
  int t = threadIdx.x;

  int   lab = labels[b*NT + t];
  float4 tb4 = ((const float4*)tboxes)[b*NT + t];
  float tcx = tb4.x, tcy = tb4.y, tw = tb4.z, th = tb4.w;
  float tx0 = tcx - 0.5f*tw, ty0 = tcy - 0.5f*th;
  float tx1 = tcx + 0.5f*tw, ty1 = tcy + 0.5f*th;
  float area2 = (tx1 - tx0) * (ty1 - ty0);

  int r0 = ch * RPC;
  u64 best = ~0ull;
  for (int rr = 0; rr < RPC; ++rr){
    int q = r0 + rr;
    size_t bq = (size_t)b*NQ + q;
    float m = stats[2*bq], s = stats[2*bq+1];      // wave-uniform
    float4 pb4 = ((const float4*)pboxes)[bq];      // wave-uniform
    float pcx = pb4.x, pcy = pb4.y, pw = pb4.z, ph = pb4.w;
    float l = logits[bq*NC + lab];                 // per-thread gather (L1/L2)
    float cclass = -(expf(l - m) / s);

    float cbbox = ((fabsf(pcx-tcx) + fabsf(pcy-tcy)) + fabsf(pw-tw)) + fabsf(ph-th);

    float px0 = pcx - 0.5f*pw, py0 = pcy - 0.5f*ph;
    float px1 = pcx + 0.5f*pw, py1 = pcy + 0.5f*ph;
    float area1 = (px1 - px0) * (py1 - py0);
    float ltx = fmaxf(px0, tx0), lty = fmaxf(py0, ty0);
    float rbx = fminf(px1, tx1), rby = fminf(py1, ty1);
    float wx = fmaxf(rbx - ltx, 0.0f), wy = fmaxf(rby - lty, 0.0f);
    float inter = wx * wy;
    float uni   = (area1 + area2) - inter;
    float iou   = inter / uni;
    float cx0 = fminf(px0, tx0), cy0 = fminf(py0, ty0);
    float cx1 = fmaxf(px1, tx1), cy1 = fmaxf(py1, ty1);
    float cwx = fmaxf(cx1 - cx0, 0.0f), cwy = fmaxf(cy1 - cy0, 0.0f);
    float areac = cwx * cwy;
    float giou  = iou - (areac - uni) / areac;

    float cost = (cclass + 5.0f*cbbox) - 2.0f*giou;
    Cout[bq*NT + t] = cost;
    u64 k = ((u64)fmono(cost) << 32) | (u32)q;
    best = k < best ? k : best;
  }
  part[((size_t)b*NCH + ch)*NT + t] = best;
}

// ---------------- kernel 2: greedy matching — 1 wave/batch, double-pop ----------------
// Per-lane 2 columns (float val, u32 meta); meta = stale<<24 | row<<7 | col.
// Round: pop1 (exact, with lazy stale rescan); then speculative pop2 from the
// same snapshot excluding col j1 — valid iff fresh && row2!=i1 && no equal-value
// candidate cached on row i1 (ballot hazard check). ~97% rounds yield 2 pops.
// Outputs buffered in registers: lane (step&63) of so0/so1,to0/to1 holds the
// step's (i,j) — i1/j1 are wave-uniform, so `if(lane==step)` deposits them.
__global__ __launch_bounds__(64) void greedy_kernel(const float* __restrict__ Cmat,
                                                    const u64* __restrict__ part,
                                                    float* __restrict__ outsrc,
                                                    float* __restrict__ outtgt){
  const int b    = blockIdx.x;
  const int lane = threadIdx.x;          // 0..63
  const float* Cb = Cmat + (size_t)b * NQ * NT;
  const u32 colA = 2*lane, colB = 2*lane + 1;

  // init: merge the 10 chunk partials per column (u64 min, order-independent)
  u64 kA = ~0ull, kB = ~0ull;
  #pragma unroll
  for (int ch = 0; ch < NCH; ++ch){
    ulonglong2 p = ((const ulonglong2*)(part + ((size_t)b * NCH + ch) * NT))[lane];
    kA = p.x < kA ? p.x : kA;
    kB = p.y < kB ? p.y : kB;
  }
  float vA = fmono_inv((u32)(kA >> 32));
  float vB = fmono_inv((u32)(kB >> 32));
  u32 mA = ((((u32)kA) & 0x3FFu) << 7) | colA;
  u32 mB = ((((u32)kB) & 0x3FFu) << 7) | colB;

  // dead-row bitmask: rd[k] bit L <=> row 64k+L dead
  u64 rd[KROWS];
  #pragma unroll
  for (int k = 0; k < KROWS; ++k) rd[k] = 0;

  int so0 = 0, so1 = 0, to0 = 0, to1 = 0;   // per-lane output slots

  int step = 0;
  while (step < NT){
    // ---- pop 1 (exact; lazy rescan of stale winners) ----
    u32 g1; float gv1;
    while (true){
      bool bsel = (vB < vA) || ((vB == vA) && (mB < mA));
      float lv = bsel ? vB : vA;
      u32   lm = bsel ? mB : mA;
      g1 = wave_argmin(lv, lm, &gv1);
      if (!(g1 >> 24)) break;
      int jj = (int)(g1 & 0x7Fu);
      float w1 = INFINITY; u32 s1 = 0;
      #pragma unroll
      for (int k = 0; k < KROWS; ++k){
        int r = lane + 64*k;
        if (r < NQ){
          float v = Cb[(size_t)r * NT + jj];
          bool dead = ((rd[k] >> lane) & 1ull) != 0ull;
          v = dead ? INFINITY : v;
          if (v < w1){ w1 = v; s1 = (u32)r; }   // ascending r -> first occurrence
        }
      }
      float rgv; u32 rrow = wave_argmin(w1, s1, &rgv);
      if (lane == (jj >> 1)){
        if (jj & 1){ vB = rgv; mB = (rrow << 7) | (u32)jj; }
        else       { vA = rgv; mA = (rrow << 7) | (u32)jj; }
      }
    }
    int i1 = (int)((g1 >> 7) & 0x3FFu);
    int j1 = (int)(g1 & 0x7Fu);
    if (step < 64){ if (lane == step)      { so0 = i1; to0 = j1; } }
    else          { if (lane == step - 64) { so1 = i1; to1 = j1; } }

    int npop = 1, i2 = 0, j2 = 0;
    if (step + 1 < NT){
      // ---- speculative pop 2: same snapshot, exclude col j1 ----
      float lv2; u32 lm2;
      if (lane == (j1 >> 1)){
        if (j1 & 1){ lv2 = vA; lm2 = mA; } else { lv2 = vB; lm2 = mB; }
      } else {
        bool bs2 = (vB < vA) || ((vB == vA) && (mB < mA));
        lv2 = bs2 ? vB : vA;
        lm2 = bs2 ? mB : mA;
      }
      float gv2; u32 g2 = wave_argmin(lv2, lm2, &gv2);
      int r2 = (int)((g2 >> 7) & 0x3FFu);
      // hazard: any other column cached on row i1 with value == gv2 (tie could
      // lex-win after i1's removal reshuffles) -> bail to single pop
      bool hzA = (vA == gv2) && (((mA >> 7) & 0x3FFu) == (u32)i1) && (colA != (u32)j1);
      bool hzB = (vB == gv2) && (((mB >> 7) & 0x3FFu) == (u32)i1) && (colB != (u32)j1);
      bool anyhz = __ballot(hzA || hzB) != 0ull;
      if (!(g2 >> 24) && r2 != i1 && !anyhz){
        i2 = r2; j2 = (int)(g2 & 0x7Fu);
        int s2 = step + 1;
        if (s2 < 64){ if (lane == s2)      { so0 = i2; to0 = j2; } }
        else        { if (lane == s2 - 64) { so1 = i2; to1 = j2; } }
        npop = 2;
      }
    }

    // ---- apply death/retirement for pop1 ----
    #pragma unroll
    for (int k = 0; k < KROWS; ++k)
      if ((i1 >> 6) == k) rd[k] |= (1ull << (i1 & 63));
    if (lane == (j1 >> 1)){
      if (j1 & 1){ vB = INFINITY; mB = 0x00FFFFFFu; }
      else       { vA = INFINITY; mA = 0x00FFFFFFu; }
    }
    if (((mA >> 7) & 0x3FFu) == (u32)i1) mA |= (1u << 24);
    if (((mB >> 7) & 0x3FFu) == (u32)i1) mB |= (1u << 24);

    if (npop == 2){
      #pragma unroll
      for (int k = 0; k < KROWS; ++k)
        if ((i2 >> 6) == k) rd[k] |= (1ull << (i2 & 63));
      if (lane == (j2 >> 1)){
        if (j2 & 1){ vB = INFINITY; mB = 0x00FFFFFFu; }
        else       { vA = INFINITY; mA = 0x00FFFFFFu; }
      }
      if (((mA >> 7) & 0x3FFu) == (u32)i2) mA |= (1u << 24);
      if (((mB >> 7) & 0x3FFu) == (u32)i2) mB |= (1u << 24);
    }
    step += npop;
  }

  // final coalesced output: lane L holds steps L and 64+L
  float* os = outsrc + b*NT;
  float* ot = outtgt + b*NT;
  os[lane]      = (float)so0;
  os[64 + lane] = (float)so1;
  ot[lane]      = (float)to0;
  ot[64 + lane] = (float)to1;
}

extern "C" void kernel_launch(void* const* d_in, const int* in_sizes, int n_in,
                              void* d_out, int out_size, void* d_ws, size_t ws_size,
                              hipStream_t stream){
  const float* logits = (const float*)d_in[0];
  const float* pboxes = (const float*)d_in[1];
  const int*   labels = (const int*)  d_in[2];
  const float* tboxes = (const float*)d_in[3];
  int B = in_sizes[0] / (NQ * NC);

  float* out    = (float*)d_out;
  float* outsrc = out;
  float* outtgt = out + (size_t)B * NT;
  float* Cmat   = out + (size_t)2 * B * NT;

  // ws layout: part (B*NCH*NT u64 = 640KB) then stats (B*NQ*2 f32 = 450KB)
  u64*   part  = (u64*)d_ws;
  float* stats = (float*)((char*)d_ws + (size_t)B * NCH * NT * sizeof(u64));

  int nrows = B * NQ;
  int blocks0 = (nrows + 3) / 4;
  softmax_stats_kernel<<<blocks0, 256, 0, stream>>>(logits, stats, nrows);

  cost_colmin_kernel<<<B * NCH, 128, 0, stream>>>(logits, pboxes, labels,
                                                  tboxes, stats, Cmat, part);

  greedy_kernel<<<B, 64, 0, stream>>>(Cmat, part, outsrc, outtgt);
}